// Round 2
// baseline (1028.322 us; speedup 1.0000x reference)
//
#include <hip/hip_runtime.h>
#include <hip/hip_bf16.h>

// Problem constants (fixed by the reference)
#define VOCAB 50000
#define D     300
#define B_    64
#define LC    32
#define T_    256
#define LT    64
#define NSEL  5

#define K4N   75                 // 300/4 float4 steps
#define CIMG  (K4N * LC * 4)     // 9600 floats per batch claim image, layout [k4][c][4]

// ws layout (floats):
//   wsC   : [B_][CIMG]   claim images, [k4][c][4] so per-k4 chunk is 512B contiguous
//   wsScr : [B_][T_]     target scores
//   wsIdx : [B_][NSEL]   top-5 indices (ints)

__device__ __forceinline__ float dot4acc(float4 c, float4 e, float a) {
    a = fmaf(c.x, e.x, a); a = fmaf(c.y, e.y, a);
    a = fmaf(c.z, e.z, a); a = fmaf(c.w, e.w, a);
    return a;
}

// ---------------- K1: gather claim embeddings into [k4][c][4] image ----------
__global__ void k_gather_claim(const int* __restrict__ claim,
                               const float* __restrict__ emb,
                               float* __restrict__ wsC) {
    int row = blockIdx.x;            // 0..B_*LC-1
    int b = row >> 5, c = row & 31;
    int tok = claim[row];
    const float* src = emb + (size_t)tok * D;
    float* dstb = wsC + (size_t)b * CIMG;
    for (int k = threadIdx.x; k < D; k += 64) {
        dstb[(k >> 2) * (LC * 4) + c * 4 + (k & 3)] = src[k];
    }
}

// Per-wave tile compute: lane l owns target column l. acc[c] = dot(claim_c, e_l).
// cb is BLOCK-uniform -> claim loads scalarize to s_load (scalar pipe, no VALU).
__device__ __forceinline__ void tile_accumulate(const float* __restrict__ cb,
                                                const float* __restrict__ erow,
                                                float acc[LC]) {
    const float4* ep = (const float4*)erow;
#pragma unroll
    for (int c = 0; c < LC; ++c) acc[c] = 0.f;
    for (int k4 = 0; k4 < K4N; ++k4) {
        float4 e = ep[k4];
        const float4* crow = (const float4*)(cb + k4 * (LC * 4));
#pragma unroll
        for (int c = 0; c < LC; ++c) acc[c] = dot4acc(crow[c], e, acc[c]);
    }
}

// ---------------- K2: target scores (1 wave = 1 tile, no LDS) ----------------
__global__ __launch_bounds__(256) void k_scores(const int* __restrict__ targets,
                                                const float* __restrict__ emb,
                                                const float* __restrict__ wsC,
                                                float* __restrict__ wsScr) {
    int lane = threadIdx.x & 63;
    int wave = threadIdx.x >> 6;
    int b = blockIdx.x >> 6;                    // uniform across block
    int t = (blockIdx.x & 63) * 4 + wave;       // wave-uniform
    int tok = targets[((size_t)b * T_ + t) * LT + lane];
    const float* erow = emb + (size_t)tok * D;
    const float* cb = wsC + (size_t)b * CIMG;

    float acc[LC];
    tile_accumulate(cb, erow, acc);

    // softmax over l (= across lanes) per c, then max over c, then sum over l
    float score = 0.f;
#pragma unroll
    for (int c = 0; c < LC; ++c) {
        float m = acc[c];
#pragma unroll
        for (int off = 32; off > 0; off >>= 1) m = fmaxf(m, __shfl_xor(m, off));
        float ex = __expf(acc[c] - m);
        float s = ex;
#pragma unroll
        for (int off = 32; off > 0; off >>= 1) s += __shfl_xor(s, off);
        score = fmaxf(score, ex / s);
    }
#pragma unroll
    for (int off = 32; off > 0; off >>= 1) score += __shfl_xor(score, off);
    if (lane == 0) wsScr[b * T_ + t] = score;
}

// ---------------- K3: top-5 per batch (descending, lowest-index ties) -----
__global__ void k_topn(const float* __restrict__ wsScr, int* __restrict__ wsIdx) {
    int b = blockIdx.x;
    int tid = threadIdx.x;              // 64 threads = 1 wave
    float v[4];
    for (int i = 0; i < 4; ++i) v[i] = wsScr[b * T_ + tid + 64 * i];
    for (int r = 0; r < NSEL; ++r) {
        float bv = v[0]; int bi = tid;
        for (int i = 1; i < 4; ++i) {
            int idx = tid + 64 * i;
            if (v[i] > bv) { bv = v[i]; bi = idx; }
        }
        for (int off = 32; off > 0; off >>= 1) {
            float ov = __shfl_down(bv, off);
            int   oi = __shfl_down(bi, off);
            if (ov > bv || (ov == bv && oi < bi)) { bv = ov; bi = oi; }
        }
        bi = __shfl(bi, 0);
        if (tid == 0) wsIdx[b * NSEL + r] = bi;
        if ((bi & 63) == tid) v[bi >> 6] = -1e30f;   // remove winner
    }
}

// ---------------- K4: recompute selected tiles, L2-normalize rows ---------
__global__ __launch_bounds__(64) void k_output(const int* __restrict__ targets,
                                               const float* __restrict__ emb,
                                               const float* __restrict__ wsC,
                                               const int* __restrict__ wsIdx,
                                               float* __restrict__ out) {
    int b = blockIdx.y, j = blockIdx.x;
    int lane = threadIdx.x;             // 64 threads = 1 wave = 1 tile
    int t = wsIdx[b * NSEL + j];        // uniform
    int tok = targets[((size_t)b * T_ + t) * LT + lane];
    const float* erow = emb + (size_t)tok * D;
    const float* cb = wsC + (size_t)b * CIMG;

    float acc[LC];
    tile_accumulate(cb, erow, acc);

    float* orow = out + (size_t)(b * NSEL + j) * (LC * LT);
#pragma unroll
    for (int c = 0; c < LC; ++c) {
        float ss = acc[c] * acc[c];
#pragma unroll
        for (int off = 32; off > 0; off >>= 1) ss += __shfl_xor(ss, off);
        orow[c * LT + lane] = acc[c] * (1.0f / sqrtf(ss));   // coalesced 256B stores
    }
}

extern "C" void kernel_launch(void* const* d_in, const int* in_sizes, int n_in,
                              void* d_out, int out_size, void* d_ws, size_t ws_size,
                              hipStream_t stream) {
    const int*   claim   = (const int*)d_in[0];
    const int*   targets = (const int*)d_in[1];
    const float* emb     = (const float*)d_in[2];
    // d_in[3] is n (=5), compile-time NSEL

    float* wsC   = (float*)d_ws;
    float* wsScr = wsC + (size_t)B_ * CIMG;
    int*   wsIdx = (int*)(wsScr + B_ * T_);
    float* out   = (float*)d_out;

    k_gather_claim<<<dim3(B_ * LC), dim3(64), 0, stream>>>(claim, emb, wsC);
    k_scores<<<dim3(B_ * 64), dim3(256), 0, stream>>>(targets, emb, wsC, wsScr);
    k_topn<<<dim3(B_), dim3(64), 0, stream>>>(wsScr, wsIdx);
    k_output<<<dim3(NSEL, B_), dim3(64), 0, stream>>>(targets, emb, wsC, wsIdx, out);
}

// Round 3
// 646.515 us; speedup vs baseline: 1.5906x; 1.5906x over previous
//
#include <hip/hip_runtime.h>
#include <hip/hip_bf16.h>

// Problem constants (fixed by the reference)
#define VOCAB 50000
#define D     300
#define B_    64
#define LC    32
#define T_    256
#define LT    64
#define NSEL  5

#define K4N   75                 // 300/4 float4 chunks per row (exact, no pad)
#define CIMG4 (K4N * LC)         // 2400 float4 per batch claim image
#define CIMG  (CIMG4 * 4)        // 9600 floats
#define TW    4                  // tiles per wave in k_scores

// ws layout (floats):
//   wsC   : [B_][CIMG]  claim images, float4-slot layout [k4][slot][4],
//                        slot = (c&3)*8 + (c>>2)  (c = cg*4+i  ->  slot = i*8+cg)
//   wsScr : [B_][T_]    target scores
//   wsIdx : [B_][NSEL]  top-5 indices (ints)

__device__ __forceinline__ float dot4acc(float4 c, float4 e, float a) {
    a = fmaf(c.x, e.x, a); a = fmaf(c.y, e.y, a);
    a = fmaf(c.z, e.z, a); a = fmaf(c.w, e.w, a);
    return a;
}

// ---------------- K1: gather claim embeddings into slot-swizzled image -------
__global__ void k_gather_claim(const int* __restrict__ claim,
                               const float* __restrict__ emb,
                               float* __restrict__ wsC) {
    int row = blockIdx.x;            // 0..B_*LC-1
    int b = row >> 5, c = row & 31;
    int slot = (c & 3) * 8 + (c >> 2);
    int tok = claim[row];
    const float* src = emb + (size_t)tok * D;
    float* dstb = wsC + (size_t)b * CIMG;
    for (int k = threadIdx.x; k < D; k += 64) {
        dstb[(k >> 2) * (LC * 4) + slot * 4 + (k & 3)] = src[k];
    }
}

// Wave-level tile: lane = lg*8+cg. acc[i][j] = dot(claim[cg*4+i], e[lg*8+j]).
// Claim reads: per (k4,i) the 8 cg-lanes hit 8 contiguous 16B chunks =
// 32 banks exactly once, 8-way broadcast across lg -> conflict-free.
__device__ __forceinline__ void wave_tile(const float4* __restrict__ sC4,
                                          const int* __restrict__ trow,
                                          const float* __restrict__ emb,
                                          int lane, float acc[4][8]) {
    int cg = lane & 7, lg = lane >> 3;
    const float4* ep[8];
#pragma unroll
    for (int j = 0; j < 8; ++j) {
        int tok = trow[lg * 8 + j];
        ep[j] = (const float4*)(emb + (size_t)tok * D);
    }
#pragma unroll
    for (int i = 0; i < 4; ++i)
#pragma unroll
        for (int j = 0; j < 8; ++j) acc[i][j] = 0.f;

#pragma unroll 1
    for (int k4 = 0; k4 < K4N; ++k4) {
        float4 e[8];
#pragma unroll
        for (int j = 0; j < 8; ++j) e[j] = ep[j][k4];
        float4 c0 = sC4[k4 * 32 + 0  + cg];
        float4 c1 = sC4[k4 * 32 + 8  + cg];
        float4 c2 = sC4[k4 * 32 + 16 + cg];
        float4 c3 = sC4[k4 * 32 + 24 + cg];
#pragma unroll
        for (int j = 0; j < 8; ++j) {
            acc[0][j] = dot4acc(c0, e[j], acc[0][j]);
            acc[1][j] = dot4acc(c1, e[j], acc[1][j]);
            acc[2][j] = dot4acc(c2, e[j], acc[2][j]);
            acc[3][j] = dot4acc(c3, e[j], acc[3][j]);
        }
    }
}

// ---------------- K2: target scores ------------------------------------------
__global__ __launch_bounds__(256) void k_scores(const int* __restrict__ targets,
                                                const float* __restrict__ emb,
                                                const float* __restrict__ wsC,
                                                float* __restrict__ wsScr) {
    __shared__ __align__(16) float4 sC4[CIMG4];   // 38400 B -> 4 blocks/CU
    int b = blockIdx.y;
    int tid = threadIdx.x;
    {
        const float4* src = (const float4*)(wsC + (size_t)b * CIMG);
        for (int i = tid; i < CIMG4; i += 256) sC4[i] = src[i];
    }
    __syncthreads();

    int lane = tid & 63, wave = tid >> 6;
    for (int tt = 0; tt < TW; ++tt) {
        int t = blockIdx.x * (4 * TW) + wave * TW + tt;
        const int* trow = targets + ((size_t)b * T_ + t) * LT;
        float acc[4][8];
        wave_tile(sC4, trow, emb, lane, acc);

        // softmax over l per c, max over c, sum over l — all in-register
        float score_l[8];
#pragma unroll
        for (int j = 0; j < 8; ++j) score_l[j] = 0.f;
#pragma unroll
        for (int i = 0; i < 4; ++i) {
            float m = acc[i][0];
#pragma unroll
            for (int j = 1; j < 8; ++j) m = fmaxf(m, acc[i][j]);
            m = fmaxf(m, __shfl_xor(m, 8));
            m = fmaxf(m, __shfl_xor(m, 16));
            m = fmaxf(m, __shfl_xor(m, 32));
            float s = 0.f;
#pragma unroll
            for (int j = 0; j < 8; ++j) { acc[i][j] = __expf(acc[i][j] - m); s += acc[i][j]; }
            s += __shfl_xor(s, 8);
            s += __shfl_xor(s, 16);
            s += __shfl_xor(s, 32);
            float r = 1.0f / s;
#pragma unroll
            for (int j = 0; j < 8; ++j) score_l[j] = fmaxf(score_l[j], acc[i][j] * r);
        }
        float tsum = 0.f;
#pragma unroll
        for (int j = 0; j < 8; ++j) {
            float v = score_l[j];
            v = fmaxf(v, __shfl_xor(v, 1));
            v = fmaxf(v, __shfl_xor(v, 2));
            v = fmaxf(v, __shfl_xor(v, 4));
            tsum += v;
        }
        tsum += __shfl_xor(tsum, 8);
        tsum += __shfl_xor(tsum, 16);
        tsum += __shfl_xor(tsum, 32);
        if (lane == 0) wsScr[b * T_ + t] = tsum;
    }
}

// ---------------- K3: top-5 per batch (descending, lowest-index ties) --------
__global__ void k_topn(const float* __restrict__ wsScr, int* __restrict__ wsIdx) {
    int b = blockIdx.x;
    int tid = threadIdx.x;              // 64 threads = 1 wave
    float v[4];
    for (int i = 0; i < 4; ++i) v[i] = wsScr[b * T_ + tid + 64 * i];
    for (int r = 0; r < NSEL; ++r) {
        float bv = v[0]; int bi = tid;
        for (int i = 1; i < 4; ++i) {
            int idx = tid + 64 * i;
            if (v[i] > bv) { bv = v[i]; bi = idx; }
        }
        for (int off = 32; off > 0; off >>= 1) {
            float ov = __shfl_down(bv, off);
            int   oi = __shfl_down(bi, off);
            if (ov > bv || (ov == bv && oi < bi)) { bv = ov; bi = oi; }
        }
        bi = __shfl(bi, 0);
        if (tid == 0) wsIdx[b * NSEL + r] = bi;
        if ((bi & 63) == tid) v[bi >> 6] = -1e30f;   // remove winner
    }
}

// ---------------- K4: recompute selected tiles, L2-normalize rows ------------
__global__ __launch_bounds__(64) void k_output(const int* __restrict__ targets,
                                               const float* __restrict__ emb,
                                               const float* __restrict__ wsC,
                                               const int* __restrict__ wsIdx,
                                               float* __restrict__ out) {
    __shared__ __align__(16) float4 sC4[CIMG4];
    int b = blockIdx.y, jj = blockIdx.x;
    int lane = threadIdx.x;             // 64 threads = 1 wave = 1 tile
    {
        const float4* src = (const float4*)(wsC + (size_t)b * CIMG);
        for (int i = lane; i < CIMG4; i += 64) sC4[i] = src[i];
    }
    __syncthreads();

    int t = wsIdx[b * NSEL + jj];
    const int* trow = targets + ((size_t)b * T_ + t) * LT;
    float acc[4][8];
    wave_tile(sC4, trow, emb, lane, acc);

    int cg = lane & 7, lg = lane >> 3;
    float* orow = out + (size_t)(b * NSEL + jj) * (LC * LT);
#pragma unroll
    for (int i = 0; i < 4; ++i) {
        float ss = 0.f;
#pragma unroll
        for (int j = 0; j < 8; ++j) ss = fmaf(acc[i][j], acc[i][j], ss);
        ss += __shfl_xor(ss, 8);
        ss += __shfl_xor(ss, 16);
        ss += __shfl_xor(ss, 32);
        float rinv = 1.0f / sqrtf(ss);
#pragma unroll
        for (int j = 0; j < 8; ++j)
            orow[(cg * 4 + i) * LT + lg * 8 + j] = acc[i][j] * rinv;
    }
}

extern "C" void kernel_launch(void* const* d_in, const int* in_sizes, int n_in,
                              void* d_out, int out_size, void* d_ws, size_t ws_size,
                              hipStream_t stream) {
    const int*   claim   = (const int*)d_in[0];
    const int*   targets = (const int*)d_in[1];
    const float* emb     = (const float*)d_in[2];
    // d_in[3] is n (=5), compile-time NSEL

    float* wsC   = (float*)d_ws;
    float* wsScr = wsC + (size_t)B_ * CIMG;
    int*   wsIdx = (int*)(wsScr + B_ * T_);
    float* out   = (float*)d_out;

    k_gather_claim<<<dim3(B_ * LC), dim3(64), 0, stream>>>(claim, emb, wsC);
    k_scores<<<dim3(T_ / (4 * TW), B_), dim3(256), 0, stream>>>(targets, emb, wsC, wsScr);
    k_topn<<<dim3(B_), dim3(64), 0, stream>>>(wsScr, wsIdx);
    k_output<<<dim3(NSEL, B_), dim3(64), 0, stream>>>(targets, emb, wsC, wsIdx, out);
}